// Round 20
// baseline (65.836 us; speedup 1.0000x reference)
//
#include <hip/hip_runtime.h>
#include <hip/hip_bf16.h>
#include <math.h>

// NVAR reservoir: out = GELU(poly_feats(x) @ W1 + b1) @ W2 + b2
// B=2 S=512 E=64 DELAY=5 -> L=320, F=51681, tokens=1024
//
// R20: R19 (best, 46.9us) extended to 4 INDEPENDENT blocks/CU:
// MT2 64->32 (At 24KB + xw 10KB + hpart 1KB ~= 35KB -> 4 blocks/CU),
// 512 threads / 8 waves, grid 1024 = 32 tiles x 32 ep, acc[2][3].
// Mechanism (R19-confirmed): co-resident independent blocks overlap one
// block's kc-loop with another's prologue/contraction. Cost: B L2-reads
// x2 (XCD-local, ~5x headroom). bid%8==ep%8 keeps R16's k_pack XCD
// alignment. kc-loop/tri-skip/k_pack/k_t/k_epi structure unchanged.

#define NF     51681
#define KPAD   352
#define KCHK   11              // 352/32
#define NFR    24              // 384/16 (frags 21..23 zero)
#define NPAD   (NFR * 16)      // 384
#define MT2    32              // tokens per tile (was 64)
#define ATS    768             // At row stride BYTES (multiple of 128)
#define XWS    40              // xw row stride (floats); 40%32=8 -> ~4-way

typedef __attribute__((ext_vector_type(8))) short short8;
typedef __attribute__((ext_vector_type(4))) float f32x4;

#define W1C_BYTES  ((size_t)64 * NF * 2)                // 6,615,168
#define MF_BYTES   ((size_t)64 * KPAD * NPAD * 2)       // 17,301,504
#define HBUF_OFF   (W1C_BYTES + MF_BYTES)

__device__ __forceinline__ unsigned short f2bf(float x) {
    return __bfloat16_as_ushort(__float2bfloat16(x));
}
__device__ __forceinline__ float bf2f(unsigned short h) {
    union { unsigned u; float f; } v; v.u = ((unsigned)h) << 16; return v.f;
}

// ---- k_t: W1c[e][f] = bf16(W1[f][e]) ----
__global__ void k_t(const float* __restrict__ W1, unsigned short* __restrict__ W1c) {
    __shared__ float t[64 * 65];
    const int tid = threadIdx.x;
    const int f0 = blockIdx.x * 64;
    #pragma unroll 1
    for (int r = 0; r < 16; ++r) {
        int idx = r * 256 + tid;
        int fi = idx >> 6, e = idx & 63;
        t[fi * 65 + e] = (f0 + fi < NF) ? W1[(size_t)(f0 + fi) * 64 + e] : 0.f;
    }
    __syncthreads();
    #pragma unroll 1
    for (int r = 0; r < 16; ++r) {
        int idx = r * 256 + tid;
        int e = idx >> 6, fi = idx & 63;
        if (f0 + fi < NF)
            W1c[(size_t)e * NF + f0 + fi] = f2bf(t[fi * 65 + e]);
    }
}

// ---- k_pack: upper-triangular M'_e, fragment order, XCD-aligned (R16) ----
__global__ void k_pack(const unsigned short* __restrict__ W1c,
                       unsigned short* __restrict__ Mfrag) {
    const int tid = threadIdx.x;
    const int x  = blockIdx.x & 7;
    const int b8 = blockIdx.x >> 3;             // 0..527
    const int c  = b8 / 66;                     // 0..7
    const int inner = b8 - c * 66;              // 0..65
    const int e = 2 * (x + 8 * (c >> 1)) + (c & 1);
    const int r264 = inner * 4 + (tid >> 6);    // rec within e, 0..263
    const int kc = r264 / 24;
    const int nf = r264 - kc * 24;
    const int lane = tid & 63;

    const int kc0o = (3 * (nf / 3)) >> 1;       // owning wave's skip start
    if (kc < kc0o) return;                      // never read by k_main

    const int i = nf * 16 + (lane & 15);
    const int jb = kc * 32 + ((lane >> 4) << 3);
    const unsigned short* wrow = W1c + (size_t)e * NF;
    const size_t g = ((size_t)(e * 264 + r264) << 6) + lane;

    __attribute__((aligned(16))) unsigned short v[8];
    #pragma unroll
    for (int r = 0; r < 8; ++r) {
        int j = jb + r;
        unsigned short out = 0;
        if (i <= j && j <= 320) {
            if (j == 320) {
                out = (i == 320) ? wrow[0] : wrow[1 + i];
            } else {
                int idx = 321 + i * 320 - ((i * (i - 1)) >> 1) + (j - i);
                out = wrow[idx];
            }
        }
        v[r] = out;
    }
    *(short8*)(Mfrag + g * 8) = *(short8*)v;
}

// ---- k_main: block = (tile of 32 tokens, e-pair). 512 thr, 4 blocks/CU ----
__global__ __launch_bounds__(512, 8) void k_main(const float* __restrict__ x,
                                                 const unsigned short* __restrict__ Mfrag,
                                                 float* __restrict__ hbuf) {
    __shared__ unsigned short At[MT2 * (ATS / 2)];  // 24KB swizzled bf16
    __shared__ float xw[64 * XWS];                  // [e][r], stride 40 (10KB)
    __shared__ float hpart[8][32];

    const int tid = threadIdx.x;
    const int bid = blockIdx.x;                 // 1024 blocks = 4/CU
    const int tile = bid >> 5;                  // 0..31
    const int ep = bid & 31;                    // XCD = ep%8 (bid%8==ep%8)
    const int e0 = ep * 2;
    const int tok0 = tile * MT2;
    const int b = tile >> 4, s0 = (tile & 15) * MT2;

    // stage xw[e][r] = x[b][s0-4+r][e], r in [0,36)
    #pragma unroll 1
    for (int idx = tid; idx < 36 * 64; idx += 512) {
        int r = idx >> 6, ee = idx & 63;
        int s = s0 - 4 + r;
        xw[ee * XWS + r] = (s >= 0) ? x[((b << 9) + s) * 64 + ee] : 0.f;
    }
    __syncthreads();

    // build A-tile: At[t][j] = bf16(d'[t][j]), 32 rows x 384 shorts, swizzled
    char* Atb = (char*)At;
    #pragma unroll 1
    for (int rec = tid; rec < MT2 * 48; rec += 512) {
        int t = rec / 48, jr = rec - t * 48;
        int j0 = jr * 8;
        __attribute__((aligned(16))) unsigned short hv[8];
        #pragma unroll
        for (int r = 0; r < 8; ++r) {
            int j = j0 + r;
            float v;
            if (j < 320) { int e5 = j / 5, k = j - e5 * 5; v = xw[e5 * XWS + t + k]; }
            else v = (j == 320) ? 1.0f : 0.f;
            hv[r] = f2bf(v);
        }
        *(short8*)(Atb + t * ATS + ((j0 * 2) ^ ((t & 7) << 4))) = *(short8*)hv;
    }
    __syncthreads();

    const int lane = tid & 63, wv = tid >> 6;   // 8 waves
    const int w3 = wv & 3;                      // SIMD s hosts wv=s,s+4 -> wn=s,7-s
    const int wn = (wv & 4) ? (7 - w3) : w3;
    const int nf0 = wn * 3;                     // uniform 3 frags per wave
    const int kc0 = (3 * wn) >> 1;              // triangular skip start
    const int arow = lane & 15;                 // + mf*16
    const int aslot = (lane >> 4) << 4;

    // contraction d-operand bases (i per q, read from xw)
    int ibase[3]; float isel1[3], isel0[3];
    #pragma unroll
    for (int q = 0; q < 3; ++q) {
        int i = (nf0 + q) * 16 + (lane & 15);
        int ic = (i < 320) ? i : 0;
        ibase[q] = (ic / 5) * XWS + (ic % 5);
        isel1[q] = (i < 320) ? 1.f : 0.f;
        isel0[q] = (i == 320) ? 1.f : 0.f;
    }

    #pragma unroll 1
    for (int eo = 0; eo < 2; ++eo) {
        const unsigned short* Bbase = Mfrag + (size_t)(e0 + eo) * (KPAD * NPAD);

        f32x4 acc[2][3];
        #pragma unroll
        for (int mf = 0; mf < 2; ++mf)
            #pragma unroll
            for (int q = 0; q < 3; ++q) acc[mf][q] = f32x4{0.f,0.f,0.f,0.f};

        short8 B0[3], B1[3];

#define BLD(DST, KCV)                                                              \
    do { if ((KCV) < KCHK) {                                                       \
        _Pragma("unroll")                                                          \
        for (int q = 0; q < 3; ++q)                                                \
            DST[q] = *(const short8*)(Bbase +                                      \
                ((size_t)(((KCV) * NFR + nf0 + q) * 64 + lane)) * 8);              \
    } } while (0)

#define STEP(KCV, CUR)                                                             \
    do {                                                                           \
        short8 Af[2];                                                              \
        _Pragma("unroll")                                                          \
        for (int mf = 0; mf < 2; ++mf) {                                           \
            int t = arow + mf * 16;                                                \
            int jb = (KCV) * 64 + aslot;                                           \
            Af[mf] = *(const short8*)(Atb + t * ATS + (jb ^ ((t & 7) << 4)));      \
        }                                                                          \
        _Pragma("unroll")                                                          \
        for (int mf = 0; mf < 2; ++mf) {                                           \
            _Pragma("unroll")                                                      \
            for (int q = 0; q < 3; ++q)                                            \
                acc[mf][q] = __builtin_amdgcn_mfma_f32_16x16x32_bf16(              \
                    Af[mf], CUR[q], acc[mf][q], 0, 0, 0);                          \
        }                                                                          \
    } while (0)

        BLD(B0, kc0);
        BLD(B1, kc0 + 1);
        int kc = kc0;
        #pragma unroll 1
        for (; kc + 1 < KCHK; kc += 2) {
            STEP(kc, B0);
            BLD(B0, kc + 2);
            STEP(kc + 1, B1);
            BLD(B1, kc + 3);
        }
        if (kc < KCHK) STEP(kc, B0);
#undef STEP
#undef BLD

        // contraction: s[mf][r] = sum_i C[t][i]*d'[t][i]; d' read from xw
        float s[2][4];
        #pragma unroll
        for (int mf = 0; mf < 2; ++mf)
            #pragma unroll
            for (int r = 0; r < 4; ++r) s[mf][r] = 0.f;

        #pragma unroll
        for (int q = 0; q < 3; ++q) {
            #pragma unroll
            for (int mf = 0; mf < 2; ++mf)
                #pragma unroll
                for (int r = 0; r < 4; ++r) {
                    int t = mf * 16 + ((lane >> 4) << 2) + r;
                    float dv = isel1[q] * xw[ibase[q] + t] + isel0[q];
                    s[mf][r] += acc[mf][q][r] * dv;
                }
        }
        #pragma unroll
        for (int mf = 0; mf < 2; ++mf)
            #pragma unroll
            for (int r = 0; r < 4; ++r) {
                float v = s[mf][r];
                v += __shfl_xor(v, 1);
                v += __shfl_xor(v, 2);
                v += __shfl_xor(v, 4);
                v += __shfl_xor(v, 8);
                s[mf][r] = v;
            }
        if ((lane & 15) == 0) {
            #pragma unroll
            for (int mf = 0; mf < 2; ++mf)
                #pragma unroll
                for (int r = 0; r < 4; ++r)
                    hpart[wn][mf * 16 + ((lane >> 4) << 2) + r] = s[mf][r];
        }
        __syncthreads();
        if (tid < 32) {
            float v = 0.f;
            #pragma unroll
            for (int w = 0; w < 8; ++w) v += hpart[w][tid];
            hbuf[(size_t)(tok0 + tid) * 64 + (e0 + eo)] = v;
        }
        __syncthreads();   // hpart reused next eo
    }
}

// ---- epilogue: out = GELU(hbuf + b1) @ W2 + b2 ----
__global__ void k_epi(const float* __restrict__ hbuf, const float* __restrict__ b1,
                      const float* __restrict__ W2, const float* __restrict__ b2,
                      float* __restrict__ out) {
    __shared__ float h[4 * 64];
    int tid = threadIdx.x;
    int t = tid >> 6, e = tid & 63;
    int token = blockIdx.x * 4 + t;
    float pre = hbuf[token * 64 + e] + b1[e];
    float hv = 0.5f * pre * (1.0f + erff(pre * 0.70710678118654752f));  // exact GELU
    h[t * 64 + e] = hv;
    __syncthreads();
    float s = b2[e];
    #pragma unroll 8
    for (int ee = 0; ee < 64; ++ee)
        s += h[t * 64 + ee] * W2[ee * 64 + e];
    out[token * 64 + e] = s;
}

extern "C" void kernel_launch(void* const* d_in, const int* in_sizes, int n_in,
                              void* d_out, int out_size, void* d_ws, size_t ws_size,
                              hipStream_t stream) {
    const float* x  = (const float*)d_in[0];
    const float* W1 = (const float*)d_in[1];
    const float* b1 = (const float*)d_in[2];
    const float* W2 = (const float*)d_in[3];
    const float* b2 = (const float*)d_in[4];
    float* out = (float*)d_out;

    unsigned short* W1c   = (unsigned short*)d_ws;
    unsigned short* Mfrag = (unsigned short*)((char*)d_ws + W1C_BYTES);
    float* hbuf           = (float*)((char*)d_ws + HBUF_OFF);

    k_t<<<(NF + 63) / 64, 256, 0, stream>>>(W1, W1c);
    k_pack<<<4224, 256, 0, stream>>>(W1c, Mfrag);          // XCD-aligned mapping
    k_main<<<1024, 512, 0, stream>>>(x, Mfrag, hbuf);
    k_epi<<<256, 256, 0, stream>>>(hbuf, b1, W2, b2, out);
}

// Round 21
// 46.767 us; speedup vs baseline: 1.4077x; 1.4077x over previous
//
#include <hip/hip_runtime.h>
#include <hip/hip_bf16.h>
#include <math.h>

// NVAR reservoir: out = GELU(poly_feats(x) @ W1 + b1) @ W2 + b2
// B=2 S=512 E=64 DELAY=5 -> L=320, F=51681, tokens=1024
//
// FINAL (= R19, session best 46.9us, absmax 0.0156, threshold 0.068):
// Bilinear formulation: h_pre[t][e] = d'^T U_e d', d' = [320 taps, 1],
// U_e upper-triangular (k_pack), K padded to 352, N to 384.
// k_main: 512 blocks (2 independent blocks/CU — overlap one block's
// kc-loop with the other's prologue/contraction; 4/CU regresses, R20:
// doubled B L2-traffic), block = (token-tile of 64) x (e-pair);
// rolled kc-loop (small I$ body, R12) with 2-deep ping-pong B prefetch
// (4-deep thrashes L2, R14), triangular kc-skip with SIMD-balanced wn
// pairs (R15), XWS=72 (~4-way not 16-way A-build bank conflicts, R15),
// contraction from xw. k_pack XCD-aligned so Mfrag producer lines land
// on the consumer's XCD L2 (R16, -4us: timed replays start L2-cold from
// harness poison fills; per-XCD L2s aren't shared).

#define NF     51681
#define KPAD   352
#define KCHK   11              // 352/32
#define NFR    24              // 384/16 (frags 21..23 zero)
#define NPAD   (NFR * 16)      // 384
#define MT2    64              // tokens per tile
#define ATS    768             // At row stride BYTES (multiple of 128)
#define XWS    72              // xw row stride (floats); 72%32=8 -> ~4-way

typedef __attribute__((ext_vector_type(8))) short short8;
typedef __attribute__((ext_vector_type(4))) float f32x4;

#define W1C_BYTES  ((size_t)64 * NF * 2)                // 6,615,168
#define MF_BYTES   ((size_t)64 * KPAD * NPAD * 2)       // 17,301,504
#define HBUF_OFF   (W1C_BYTES + MF_BYTES)

__device__ __forceinline__ unsigned short f2bf(float x) {
    return __bfloat16_as_ushort(__float2bfloat16(x));
}
__device__ __forceinline__ float bf2f(unsigned short h) {
    union { unsigned u; float f; } v; v.u = ((unsigned)h) << 16; return v.f;
}

// ---- k_t: W1c[e][f] = bf16(W1[f][e]) ----
__global__ void k_t(const float* __restrict__ W1, unsigned short* __restrict__ W1c) {
    __shared__ float t[64 * 65];
    const int tid = threadIdx.x;
    const int f0 = blockIdx.x * 64;
    #pragma unroll 1
    for (int r = 0; r < 16; ++r) {
        int idx = r * 256 + tid;
        int fi = idx >> 6, e = idx & 63;
        t[fi * 65 + e] = (f0 + fi < NF) ? W1[(size_t)(f0 + fi) * 64 + e] : 0.f;
    }
    __syncthreads();
    #pragma unroll 1
    for (int r = 0; r < 16; ++r) {
        int idx = r * 256 + tid;
        int e = idx >> 6, fi = idx & 63;
        if (f0 + fi < NF)
            W1c[(size_t)e * NF + f0 + fi] = f2bf(t[fi * 65 + e]);
    }
}

// ---- k_pack: upper-triangular M'_e, fragment order, XCD-aligned (R16) ----
__global__ void k_pack(const unsigned short* __restrict__ W1c,
                       unsigned short* __restrict__ Mfrag) {
    const int tid = threadIdx.x;
    const int x  = blockIdx.x & 7;
    const int b8 = blockIdx.x >> 3;             // 0..527
    const int c  = b8 / 66;                     // 0..7
    const int inner = b8 - c * 66;              // 0..65
    const int e = 2 * (x + 8 * (c >> 1)) + (c & 1);
    const int r264 = inner * 4 + (tid >> 6);    // rec within e, 0..263
    const int kc = r264 / 24;
    const int nf = r264 - kc * 24;
    const int lane = tid & 63;

    const int kc0o = (3 * (nf / 3)) >> 1;       // owning wave's skip start
    if (kc < kc0o) return;                      // never read by k_main

    const int i = nf * 16 + (lane & 15);
    const int jb = kc * 32 + ((lane >> 4) << 3);
    const unsigned short* wrow = W1c + (size_t)e * NF;
    const size_t g = ((size_t)(e * 264 + r264) << 6) + lane;

    __attribute__((aligned(16))) unsigned short v[8];
    #pragma unroll
    for (int r = 0; r < 8; ++r) {
        int j = jb + r;
        unsigned short out = 0;
        if (i <= j && j <= 320) {
            if (j == 320) {
                out = (i == 320) ? wrow[0] : wrow[1 + i];
            } else {
                int idx = 321 + i * 320 - ((i * (i - 1)) >> 1) + (j - i);
                out = wrow[idx];
            }
        }
        v[r] = out;
    }
    *(short8*)(Mfrag + g * 8) = *(short8*)v;
}

// ---- k_main: block = (tile of 64 tokens, e-pair). 512 thr, 2 blocks/CU ----
__global__ __launch_bounds__(512, 4) void k_main(const float* __restrict__ x,
                                                 const unsigned short* __restrict__ Mfrag,
                                                 float* __restrict__ hbuf) {
    __shared__ unsigned short At[MT2 * (ATS / 2)];  // 48KB swizzled bf16
    __shared__ float xw[64 * XWS];                  // [e][r], stride 72 (18KB)
    __shared__ float hpart[8][64];

    const int tid = threadIdx.x;
    const int bid = blockIdx.x;                 // 512 blocks = 2/CU
    const int tile = bid >> 5;                  // 0..15
    const int ep = bid & 31;                    // XCD = ep%8 (bid%8==ep%8)
    const int e0 = ep * 2;
    const int tok0 = tile * MT2;
    const int b = tile >> 3, s0 = (tile & 7) * MT2;

    // stage xw[e][r] = x[b][s0-4+r][e], r in [0,68)
    #pragma unroll 1
    for (int idx = tid; idx < 68 * 64; idx += 512) {
        int r = idx >> 6, ee = idx & 63;
        int s = s0 - 4 + r;
        xw[ee * XWS + r] = (s >= 0) ? x[((b << 9) + s) * 64 + ee] : 0.f;
    }
    __syncthreads();

    // build A-tile: At[t][j] = bf16(d'[t][j]), 64 rows x 384 shorts, swizzled
    char* Atb = (char*)At;
    #pragma unroll 1
    for (int rec = tid; rec < MT2 * 48; rec += 512) {
        int t = rec / 48, jr = rec - t * 48;
        int j0 = jr * 8;
        __attribute__((aligned(16))) unsigned short hv[8];
        #pragma unroll
        for (int r = 0; r < 8; ++r) {
            int j = j0 + r;
            float v;
            if (j < 320) { int e5 = j / 5, k = j - e5 * 5; v = xw[e5 * XWS + t + k]; }
            else v = (j == 320) ? 1.0f : 0.f;
            hv[r] = f2bf(v);
        }
        *(short8*)(Atb + t * ATS + ((j0 * 2) ^ ((t & 7) << 4))) = *(short8*)hv;
    }
    __syncthreads();

    const int lane = tid & 63, wv = tid >> 6;   // 8 waves
    const int w3 = wv & 3;                      // SIMD s hosts wv=s,s+4 -> wn=s,7-s
    const int wn = (wv & 4) ? (7 - w3) : w3;
    const int nf0 = wn * 3;                     // uniform 3 frags per wave
    const int kc0 = (3 * wn) >> 1;              // triangular skip start
    const int arow = lane & 15;                 // + mf*16
    const int aslot = (lane >> 4) << 4;

    // contraction d-operand bases (i per q, read from xw)
    int ibase[3]; float isel1[3], isel0[3];
    #pragma unroll
    for (int q = 0; q < 3; ++q) {
        int i = (nf0 + q) * 16 + (lane & 15);
        int ic = (i < 320) ? i : 0;
        ibase[q] = (ic / 5) * XWS + (ic % 5);
        isel1[q] = (i < 320) ? 1.f : 0.f;
        isel0[q] = (i == 320) ? 1.f : 0.f;
    }

    #pragma unroll 1
    for (int eo = 0; eo < 2; ++eo) {
        const unsigned short* Bbase = Mfrag + (size_t)(e0 + eo) * (KPAD * NPAD);

        f32x4 acc[4][3];
        #pragma unroll
        for (int mf = 0; mf < 4; ++mf)
            #pragma unroll
            for (int q = 0; q < 3; ++q) acc[mf][q] = f32x4{0.f,0.f,0.f,0.f};

        short8 B0[3], B1[3];

#define BLD(DST, KCV)                                                              \
    do { if ((KCV) < KCHK) {                                                       \
        _Pragma("unroll")                                                          \
        for (int q = 0; q < 3; ++q)                                                \
            DST[q] = *(const short8*)(Bbase +                                      \
                ((size_t)(((KCV) * NFR + nf0 + q) * 64 + lane)) * 8);              \
    } } while (0)

#define STEP(KCV, CUR)                                                             \
    do {                                                                           \
        short8 Af[4];                                                              \
        _Pragma("unroll")                                                          \
        for (int mf = 0; mf < 4; ++mf) {                                           \
            int t = arow + mf * 16;                                                \
            int jb = (KCV) * 64 + aslot;                                           \
            Af[mf] = *(const short8*)(Atb + t * ATS + (jb ^ ((t & 7) << 4)));      \
        }                                                                          \
        _Pragma("unroll")                                                          \
        for (int mf = 0; mf < 4; ++mf) {                                           \
            _Pragma("unroll")                                                      \
            for (int q = 0; q < 3; ++q)                                            \
                acc[mf][q] = __builtin_amdgcn_mfma_f32_16x16x32_bf16(              \
                    Af[mf], CUR[q], acc[mf][q], 0, 0, 0);                          \
        }                                                                          \
    } while (0)

        BLD(B0, kc0);
        BLD(B1, kc0 + 1);
        int kc = kc0;
        #pragma unroll 1
        for (; kc + 1 < KCHK; kc += 2) {
            STEP(kc, B0);
            BLD(B0, kc + 2);
            STEP(kc + 1, B1);
            BLD(B1, kc + 3);
        }
        if (kc < KCHK) STEP(kc, B0);
#undef STEP
#undef BLD

        // contraction: s[mf][r] = sum_i C[t][i]*d'[t][i]; d' read from xw
        float s[4][4];
        #pragma unroll
        for (int mf = 0; mf < 4; ++mf)
            #pragma unroll
            for (int r = 0; r < 4; ++r) s[mf][r] = 0.f;

        #pragma unroll
        for (int q = 0; q < 3; ++q) {
            #pragma unroll
            for (int mf = 0; mf < 4; ++mf)
                #pragma unroll
                for (int r = 0; r < 4; ++r) {
                    int t = mf * 16 + ((lane >> 4) << 2) + r;
                    float dv = isel1[q] * xw[ibase[q] + t] + isel0[q];
                    s[mf][r] += acc[mf][q][r] * dv;
                }
        }
        #pragma unroll
        for (int mf = 0; mf < 4; ++mf)
            #pragma unroll
            for (int r = 0; r < 4; ++r) {
                float v = s[mf][r];
                v += __shfl_xor(v, 1);
                v += __shfl_xor(v, 2);
                v += __shfl_xor(v, 4);
                v += __shfl_xor(v, 8);
                s[mf][r] = v;
            }
        if ((lane & 15) == 0) {
            #pragma unroll
            for (int mf = 0; mf < 4; ++mf)
                #pragma unroll
                for (int r = 0; r < 4; ++r)
                    hpart[wn][mf * 16 + ((lane >> 4) << 2) + r] = s[mf][r];
        }
        __syncthreads();
        if (tid < 64) {
            float v = 0.f;
            #pragma unroll
            for (int w = 0; w < 8; ++w) v += hpart[w][tid];
            hbuf[(size_t)(tok0 + tid) * 64 + (e0 + eo)] = v;
        }
        __syncthreads();   // hpart reused next eo
    }
}

// ---- epilogue: out = GELU(hbuf + b1) @ W2 + b2 ----
__global__ void k_epi(const float* __restrict__ hbuf, const float* __restrict__ b1,
                      const float* __restrict__ W2, const float* __restrict__ b2,
                      float* __restrict__ out) {
    __shared__ float h[4 * 64];
    int tid = threadIdx.x;
    int t = tid >> 6, e = tid & 63;
    int token = blockIdx.x * 4 + t;
    float pre = hbuf[token * 64 + e] + b1[e];
    float hv = 0.5f * pre * (1.0f + erff(pre * 0.70710678118654752f));  // exact GELU
    h[t * 64 + e] = hv;
    __syncthreads();
    float s = b2[e];
    #pragma unroll 8
    for (int ee = 0; ee < 64; ++ee)
        s += h[t * 64 + ee] * W2[ee * 64 + e];
    out[token * 64 + e] = s;
}

extern "C" void kernel_launch(void* const* d_in, const int* in_sizes, int n_in,
                              void* d_out, int out_size, void* d_ws, size_t ws_size,
                              hipStream_t stream) {
    const float* x  = (const float*)d_in[0];
    const float* W1 = (const float*)d_in[1];
    const float* b1 = (const float*)d_in[2];
    const float* W2 = (const float*)d_in[3];
    const float* b2 = (const float*)d_in[4];
    float* out = (float*)d_out;

    unsigned short* W1c   = (unsigned short*)d_ws;
    unsigned short* Mfrag = (unsigned short*)((char*)d_ws + W1C_BYTES);
    float* hbuf           = (float*)((char*)d_ws + HBUF_OFF);

    k_t<<<(NF + 63) / 64, 256, 0, stream>>>(W1, W1c);
    k_pack<<<4224, 256, 0, stream>>>(W1c, Mfrag);          // XCD-aligned mapping
    k_main<<<512, 512, 0, stream>>>(x, Mfrag, hbuf);
    k_epi<<<256, 256, 0, stream>>>(hbuf, b1, W2, b2, out);
}